// Round 1
// baseline (1695.790 us; speedup 1.0000x reference)
//
#include <hip/hip_runtime.h>
#include <stdint.h>

// ---------------------------------------------------------------------------
// Ternary (sign/zero) 3x3 conv block via bitplane popcount.
//
// Layouts:
//   Packed activations A/B: uint32 [n][58][58][16] (halo of 1 pixel, zeroed).
//     Per pixel, word[2k] = sign bits of channels 32k..32k+31 (bit i = ch 32k+i
//     is negative), word[2k+1] = nonzero bits.
//   Packed weights Wp: uint32 [k][tap][plane][co]  (k=0..7 channel word,
//     tap=kh*3+kw, plane 0=sign 1=nonzero, co=0..255) -> coalesced over co.
//
// dot(32ch) = popc(nzA & nzW) - 2*popc((sgA ^ sgW) & nzA & nzW)
// ---------------------------------------------------------------------------

#define NB 64
#define C  256
#define H  56
#define W  56
#define HP 58          // padded spatial
#define PW 16          // uint32 words per packed pixel (8 sign + 8 nz interleaved)
#define KW 8           // 32-bit channel words

__device__ __forceinline__ size_t apix(int n, int hr, int wc) {
    return (((size_t)n * HP + hr) * HP + wc) * PW;
}

__global__ __launch_bounds__(256)
void pack_input_kernel(const float* __restrict__ x, uint32_t* __restrict__ A) {
    const int h = blockIdx.x, n = blockIdx.y;
    const int wv = threadIdx.x >> 6, lane = threadIdx.x & 63;
    const int ci = wv * 64 + lane;
    const float* xp = x + ((size_t)(n * C + ci) * H + h) * W;
    uint32_t* op = A + apix(n, h + 1, 1) + wv * 4;
    for (int w = 0; w < W; ++w) {
        float v = xp[w];
        unsigned long long sg = __ballot(v < 0.0f);
        unsigned long long nz = __ballot(v != 0.0f);
        if (lane == 0) {
            uint4 val;
            val.x = (uint32_t)sg;          // sign word k=2*wv
            val.y = (uint32_t)nz;          // nz   word k=2*wv
            val.z = (uint32_t)(sg >> 32);  // sign word k=2*wv+1
            val.w = (uint32_t)(nz >> 32);  // nz   word k=2*wv+1
            *(uint4*)(op + (size_t)w * PW) = val;
        }
    }
}

__global__ __launch_bounds__(64)
void pack_weights_kernel(const float* __restrict__ wa, const float* __restrict__ wb,
                         uint32_t* __restrict__ Wpa, uint32_t* __restrict__ Wpb) {
    const int tap = blockIdx.x;   // 0..8
    const int co  = blockIdx.y;   // 0..255
    const float* w = blockIdx.z ? wb : wa;
    uint32_t* Wp   = blockIdx.z ? Wpb : Wpa;
    const int lane = threadIdx.x;
    for (int g = 0; g < 4; ++g) {
        int ci = g * 64 + lane;
        float v = w[((size_t)co * C + ci) * 9 + tap];
        unsigned long long sg = __ballot(v < 0.0f);
        unsigned long long nz = __ballot(v != 0.0f);
        if (lane == 0) {
            int k0 = 2 * g;
            Wp[(((k0    ) * 9 + tap) * 2 + 0) * C + co] = (uint32_t)sg;
            Wp[(((k0    ) * 9 + tap) * 2 + 1) * C + co] = (uint32_t)nz;
            Wp[(((k0 + 1) * 9 + tap) * 2 + 0) * C + co] = (uint32_t)(sg >> 32);
            Wp[(((k0 + 1) * 9 + tap) * 2 + 1) * C + co] = (uint32_t)(nz >> 32);
        }
    }
}

// STAGE 1: dot -> BN -> (hardtanh) -> pack sign/nz bitplanes for conv2.
// STAGE 2: dot -> BN -> + residual -> clip [-1,1] -> fp32 out.
template <int STAGE>
__global__ __launch_bounds__(256)
void bconv_kernel(const uint32_t* __restrict__ A, const uint32_t* __restrict__ Wp,
                  const float* __restrict__ gamma, const float* __restrict__ beta,
                  const float* __restrict__ mean,  const float* __restrict__ var,
                  const float* __restrict__ resid,
                  uint32_t* __restrict__ Bout,
                  float* __restrict__ out) {
    const int h = blockIdx.x, n = blockIdx.y;
    const int co = threadIdx.x;
    const int wv = co >> 6, lane = co & 63;

    // BN constants in double for a close match to the numpy reference.
    double sc_d = (double)gamma[co] / sqrt((double)var[co] + 1e-5);
    float scale = (float)sc_d;
    float shift = (float)((double)beta[co] - (double)mean[co] * sc_d);

    const size_t rowbase = ((size_t)n * HP + h) * HP;  // output (h,w) tap (r,c) -> buf pixel (h+r, w+c)

    for (int ws = 0; ws < W; ws += 8) {
        int acc1[8], acc2[8];
#pragma unroll
        for (int p = 0; p < 8; ++p) { acc1[p] = 0; acc2[p] = 0; }

#pragma unroll 1
        for (int k = 0; k < KW; ++k) {
            uint32_t wsg[9], wnz[9];
#pragma unroll
            for (int t = 0; t < 9; ++t) {
                wsg[t] = Wp[((k * 9 + t) * 2 + 0) * C + co];
                wnz[t] = Wp[((k * 9 + t) * 2 + 1) * C + co];
            }
#pragma unroll
            for (int p = 0; p < 8; ++p) {
                const int w = ws + p;
#pragma unroll
                for (int r = 0; r < 3; ++r) {
#pragma unroll
                    for (int c = 0; c < 3; ++c) {
                        const uint32_t* ap =
                            A + ((rowbase + (size_t)r * HP + (w + c)) * PW + 2 * k);
                        uint32_t as = ap[0];
                        uint32_t an = ap[1];
                        const int t = r * 3 + c;
                        uint32_t m = an & wnz[t];
                        uint32_t d = (as ^ wsg[t]) & m;
                        acc1[p] += __popc(m);
                        acc2[p] += __popc(d);
                    }
                }
            }
        }

        // epilogue for this strip
#pragma unroll
        for (int p = 0; p < 8; ++p) {
            const int w = ws + p;
            const int dot = acc1[p] - 2 * acc2[p];
            // keep mul+add separate (no contraction) to mirror reference x*scale+shift
            float v = __fadd_rn(__fmul_rn((float)dot, scale), shift);
            if (STAGE == 1) {
                // hardtanh preserves sign and zero-ness; only bitplanes needed.
                unsigned long long sg = __ballot(v < 0.0f);
                unsigned long long nz = __ballot(v != 0.0f);
                if (lane == 0) {
                    uint4 val;
                    val.x = (uint32_t)sg;
                    val.y = (uint32_t)nz;
                    val.z = (uint32_t)(sg >> 32);
                    val.w = (uint32_t)(nz >> 32);
                    *(uint4*)(Bout + apix(n, h + 1, w + 1) + wv * 4) = val;
                }
            } else {
                size_t oidx = ((size_t)(n * C + co) * H + h) * W + w;
                float o = v + resid[oidx];
                o = fminf(1.0f, fmaxf(-1.0f, o));
                out[oidx] = o;
            }
        }
    }
}

extern "C" void kernel_launch(void* const* d_in, const int* in_sizes, int n_in,
                              void* d_out, int out_size, void* d_ws, size_t ws_size,
                              hipStream_t stream) {
    const float* x  = (const float*)d_in[0];
    const float* w1 = (const float*)d_in[1];
    const float* g1 = (const float*)d_in[2];
    const float* b1 = (const float*)d_in[3];
    const float* m1 = (const float*)d_in[4];
    const float* v1 = (const float*)d_in[5];
    const float* w2 = (const float*)d_in[6];
    const float* g2 = (const float*)d_in[7];
    const float* b2 = (const float*)d_in[8];
    const float* m2 = (const float*)d_in[9];
    const float* v2 = (const float*)d_in[10];
    float* out = (float*)d_out;

    uint8_t* ws = (uint8_t*)d_ws;
    const size_t SZ  = (size_t)NB * HP * HP * PW * 4;  // 13,778,944 B per packed act buffer
    const size_t WSZ = (size_t)KW * 9 * 2 * C * 4;     // 147,456 B per packed weight
    uint32_t* A   = (uint32_t*)(ws);
    uint32_t* B   = (uint32_t*)(ws + SZ);
    uint32_t* Wp1 = (uint32_t*)(ws + 2 * SZ);
    uint32_t* Wp2 = (uint32_t*)(ws + 2 * SZ + WSZ);

    // zero both packed activation buffers (gives us the zero halos; interiors
    // are fully overwritten by pack_input / stage-1 epilogue)
    hipMemsetAsync(ws, 0, 2 * SZ, stream);

    pack_weights_kernel<<<dim3(9, 256, 2), 64, 0, stream>>>(w1, w2, Wp1, Wp2);
    pack_input_kernel<<<dim3(H, NB), 256, 0, stream>>>(x, A);
    bconv_kernel<1><<<dim3(H, NB), 256, 0, stream>>>(A, Wp1, g1, b1, m1, v1,
                                                     nullptr, B, nullptr);
    bconv_kernel<2><<<dim3(H, NB), 256, 0, stream>>>(B, Wp2, g2, b2, m2, v2,
                                                     x, nullptr, out);
}

// Round 2
// 1040.680 us; speedup vs baseline: 1.6295x; 1.6295x over previous
//
#include <hip/hip_runtime.h>
#include <stdint.h>

// ---------------------------------------------------------------------------
// Ternary (sign/zero) 3x3 conv block via bitplane popcount, with scalar-pipe
// offload for the (overwhelmingly common) all-nonzero-weight case.
//
// Packed activations A/B: uint32 [n][58][58][16] (1-pixel halo, zeroed).
//   word[2k]   = sign bits of channels 32k..32k+31
//   word[2k+1] = nonzero bits
// Packed weights Wp: uint32 [k][tap][plane][co], coalesced over co.
//
// dot(32ch) = popc(nzA & nzW) - 2*popc((sgA ^ sgW) & nzA & nzW)
// Fast path P1 (all weights nonzero): m = nzA  -> popc(m) is lane-independent,
//   accumulate on scalar pipe; VALU does xor+and+bcnt (3 ops) per tap.
// Fast path P2 (P1 + all activations nonzero): popc(m)=32, VALU xor+bcnt (2).
// ---------------------------------------------------------------------------

#define NB 64
#define C  256
#define H  56
#define W  56
#define HP 58
#define PW 16
#define KW 8

__device__ __forceinline__ size_t apix(int n, int hr, int wc) {
    return (((size_t)n * HP + hr) * HP + wc) * PW;
}

__global__ __launch_bounds__(256)
void pack_input_kernel(const float* __restrict__ x, uint32_t* __restrict__ A) {
    const int h = blockIdx.x, n = blockIdx.y;
    const int wv = threadIdx.x >> 6, lane = threadIdx.x & 63;
    const int ci = wv * 64 + lane;
    const float4* xp = (const float4*)(x + ((size_t)(n * C + ci) * H + h) * W);

    // 14 independent float4 gathers -> full-row in registers (ILP hides latency)
    float4 v[14];
#pragma unroll
    for (int i = 0; i < 14; ++i) v[i] = xp[i];

    __shared__ uint32_t st[4][56][4];   // [wv][w][word]
#pragma unroll
    for (int i = 0; i < 14; ++i) {
        float vv[4] = {v[i].x, v[i].y, v[i].z, v[i].w};
#pragma unroll
        for (int j = 0; j < 4; ++j) {
            unsigned long long sg = __ballot(vv[j] < 0.0f);
            unsigned long long nz = __ballot(vv[j] != 0.0f);
            if (lane == 0) {
                int w = 4 * i + j;
                st[wv][w][0] = (uint32_t)sg;
                st[wv][w][1] = (uint32_t)nz;
                st[wv][w][2] = (uint32_t)(sg >> 32);
                st[wv][w][3] = (uint32_t)(nz >> 32);
            }
        }
    }
    __syncthreads();
    // coalesced block write: 56 pixels x 16 words contiguous at (h+1, 1)
    uint32_t* dst = A + apix(n, h + 1, 1);
    for (int idx = threadIdx.x; idx < 56 * 16; idx += 256) {
        int w = idx >> 4, wo = idx & 15;          // wo = wv*4 + word
        dst[idx] = st[wo >> 2][w][wo & 3];
    }
}

__global__ __launch_bounds__(64)
void pack_weights_kernel(const float* __restrict__ wa, const float* __restrict__ wb,
                         uint32_t* __restrict__ Wpa, uint32_t* __restrict__ Wpb) {
    const int tap = blockIdx.x;   // 0..8
    const int co  = blockIdx.y;   // 0..255
    const float* w = blockIdx.z ? wb : wa;
    uint32_t* Wp   = blockIdx.z ? Wpb : Wpa;
    const int lane = threadIdx.x;
    for (int g = 0; g < 4; ++g) {
        int ci = g * 64 + lane;
        float v = w[((size_t)co * C + ci) * 9 + tap];
        unsigned long long sg = __ballot(v < 0.0f);
        unsigned long long nz = __ballot(v != 0.0f);
        if (lane == 0) {
            int k0 = 2 * g;
            Wp[(((k0    ) * 9 + tap) * 2 + 0) * C + co] = (uint32_t)sg;
            Wp[(((k0    ) * 9 + tap) * 2 + 1) * C + co] = (uint32_t)nz;
            Wp[(((k0 + 1) * 9 + tap) * 2 + 0) * C + co] = (uint32_t)(sg >> 32);
            Wp[(((k0 + 1) * 9 + tap) * 2 + 1) * C + co] = (uint32_t)(nz >> 32);
        }
    }
}

// STAGE 1: dot -> BN -> (hardtanh) -> pack sign/nz bitplanes for conv2.
// STAGE 2: dot -> BN -> + residual -> clip [-1,1] -> fp32 out.
template <int STAGE>
__global__ __launch_bounds__(256)
void bconv_kernel(const uint32_t* __restrict__ A, const uint32_t* __restrict__ Wp,
                  const float* __restrict__ gamma, const float* __restrict__ beta,
                  const float* __restrict__ mean,  const float* __restrict__ var,
                  const float* __restrict__ resid,
                  uint32_t* __restrict__ Bout,
                  float* __restrict__ out) {
    const int h = blockIdx.x, n = blockIdx.y;
    const int co = threadIdx.x;
    const int wv = co >> 6, lane = co & 63;

    double sc_d = (double)gamma[co] / sqrt((double)var[co] + 1e-5);
    float scale = (float)sc_d;
    float shift = (float)((double)beta[co] - (double)mean[co] * sc_d);

    const size_t rowbase = ((size_t)n * HP + h) * HP;

    for (int ws = 0; ws < W; ws += 8) {
        int vacc1[8], acc2[8], sacc[8];
#pragma unroll
        for (int p = 0; p < 8; ++p) { vacc1[p] = 0; acc2[p] = 0; sacc[p] = 0; }

#pragma unroll 1
        for (int k = 0; k < KW; ++k) {
            // per-co weight words (VGPR)
            uint32_t wsg[9], wnz[9];
#pragma unroll
            for (int t = 0; t < 9; ++t) {
                wsg[t] = Wp[((k * 9 + t) * 2 + 0) * C + co];
                wnz[t] = Wp[((k * 9 + t) * 2 + 1) * C + co];
            }
            // wave-uniform activation window (compiler -> s_load_dwordx2)
            uint32_t as_[3][10], an_[3][10];
#pragma unroll
            for (int r = 0; r < 3; ++r) {
#pragma unroll
                for (int c = 0; c < 10; ++c) {
                    const uint32_t* ap =
                        A + ((rowbase + (size_t)r * HP + (ws + c)) * PW + 2 * k);
                    as_[r][c] = ap[0];
                    an_[r][c] = ap[1];
                }
            }

            uint32_t wall = wnz[0];
#pragma unroll
            for (int t = 1; t < 9; ++t) wall &= wnz[t];

            if (__all((int)(wall == 0xFFFFFFFFu))) {
                uint32_t aall = 0xFFFFFFFFu;
#pragma unroll
                for (int r = 0; r < 3; ++r)
#pragma unroll
                    for (int c = 0; c < 10; ++c) aall &= an_[r][c];

                if (aall == 0xFFFFFFFFu) {
                    // P2: weights & activations all nonzero: 2 VALU / tap
#pragma unroll
                    for (int p = 0; p < 8; ++p) {
                        sacc[p] += 9 * 32;
#pragma unroll
                        for (int r = 0; r < 3; ++r)
#pragma unroll
                            for (int c = 0; c < 3; ++c)
                                acc2[p] += __popc(as_[r][p + c] ^ wsg[r * 3 + c]);
                    }
                } else {
                    // P1: weights all nonzero: popc(m) lane-independent (scalar)
                    int pa[3][10];
#pragma unroll
                    for (int r = 0; r < 3; ++r)
#pragma unroll
                        for (int c = 0; c < 10; ++c) pa[r][c] = __popc(an_[r][c]);
                    int cs[10];
#pragma unroll
                    for (int c = 0; c < 10; ++c)
                        cs[c] = pa[0][c] + pa[1][c] + pa[2][c];
#pragma unroll
                    for (int p = 0; p < 8; ++p) {
                        sacc[p] += cs[p] + cs[p + 1] + cs[p + 2];
#pragma unroll
                        for (int r = 0; r < 3; ++r)
#pragma unroll
                            for (int c = 0; c < 3; ++c) {
                                uint32_t d = (as_[r][p + c] ^ wsg[r * 3 + c]) & an_[r][p + c];
                                acc2[p] += __popc(d);
                            }
                    }
                }
            } else {
                // P0: exact general ternary path
#pragma unroll
                for (int p = 0; p < 8; ++p) {
#pragma unroll
                    for (int r = 0; r < 3; ++r)
#pragma unroll
                        for (int c = 0; c < 3; ++c) {
                            const int t = r * 3 + c;
                            uint32_t m = an_[r][p + c] & wnz[t];
                            uint32_t d = (as_[r][p + c] ^ wsg[t]) & m;
                            vacc1[p] += __popc(m);
                            acc2[p] += __popc(d);
                        }
                }
            }
        }

        // epilogue for this strip
#pragma unroll
        for (int p = 0; p < 8; ++p) {
            const int w = ws + p;
            const int dot = sacc[p] + vacc1[p] - 2 * acc2[p];
            float v = __fadd_rn(__fmul_rn((float)dot, scale), shift);
            if (STAGE == 1) {
                unsigned long long sg = __ballot(v < 0.0f);
                unsigned long long nz = __ballot(v != 0.0f);
                if (lane == 0) {
                    uint4 val;
                    val.x = (uint32_t)sg;
                    val.y = (uint32_t)nz;
                    val.z = (uint32_t)(sg >> 32);
                    val.w = (uint32_t)(nz >> 32);
                    *(uint4*)(Bout + apix(n, h + 1, w + 1) + wv * 4) = val;
                }
            } else {
                size_t oidx = ((size_t)(n * C + co) * H + h) * W + w;
                float o = v + resid[oidx];
                o = fminf(1.0f, fmaxf(-1.0f, o));
                out[oidx] = o;
            }
        }
    }
}

extern "C" void kernel_launch(void* const* d_in, const int* in_sizes, int n_in,
                              void* d_out, int out_size, void* d_ws, size_t ws_size,
                              hipStream_t stream) {
    const float* x  = (const float*)d_in[0];
    const float* w1 = (const float*)d_in[1];
    const float* g1 = (const float*)d_in[2];
    const float* b1 = (const float*)d_in[3];
    const float* m1 = (const float*)d_in[4];
    const float* v1 = (const float*)d_in[5];
    const float* w2 = (const float*)d_in[6];
    const float* g2 = (const float*)d_in[7];
    const float* b2 = (const float*)d_in[8];
    const float* m2 = (const float*)d_in[9];
    const float* v2 = (const float*)d_in[10];
    float* out = (float*)d_out;

    uint8_t* ws = (uint8_t*)d_ws;
    const size_t SZ  = (size_t)NB * HP * HP * PW * 4;  // packed act buffer bytes
    const size_t WSZ = (size_t)KW * 9 * 2 * C * 4;     // packed weight bytes
    uint32_t* A   = (uint32_t*)(ws);
    uint32_t* B   = (uint32_t*)(ws + SZ);
    uint32_t* Wp1 = (uint32_t*)(ws + 2 * SZ);
    uint32_t* Wp2 = (uint32_t*)(ws + 2 * SZ + WSZ);

    // zero halos of both packed activation buffers
    hipMemsetAsync(ws, 0, 2 * SZ, stream);

    pack_weights_kernel<<<dim3(9, 256, 2), 64, 0, stream>>>(w1, w2, Wp1, Wp2);
    pack_input_kernel<<<dim3(H, NB), 256, 0, stream>>>(x, A);
    bconv_kernel<1><<<dim3(H, NB), 256, 0, stream>>>(A, Wp1, g1, b1, m1, v1,
                                                     nullptr, B, nullptr);
    bconv_kernel<2><<<dim3(H, NB), 256, 0, stream>>>(B, Wp2, g2, b2, m2, v2,
                                                     x, nullptr, out);
}

// Round 3
// 666.305 us; speedup vs baseline: 2.5451x; 1.5619x over previous
//
#include <hip/hip_runtime.h>
#include <stdint.h>

// ---------------------------------------------------------------------------
// Ternary 3x3 conv block via i8 MFMA implicit GEMM.
//
// Activations: NHWC i8 ternary {-1,0,+1}, padded [64][58][58][256], halo = 0.
// Weights: pre-packed into exact MFMA B-fragment order:
//   Bpk[nfrag(16)][kstep(36)][lane(64)][16B], k = tap*256 + ci,
//   value(k, co=nfrag*16+lane%16) at bytes j: k = kstep*64 + (lane/16)*16 + j.
// Conv kernel: per block (n, h-pair): M=112 pixels x N=256 co x K=2304.
//   Stage 4 input rows -> LDS (63 KB, 272B/pixel pad); K-loop = LDS + L2 only.
//   D = A.B via v_mfma_i32_16x16x64_i8; C/D: col=lane&15, row=(lane>>4)*4+reg.
// ---------------------------------------------------------------------------

#define NB 64
#define C  256
#define H  56
#define W  56
#define HP 58
#define PPIX 272                 // padded bytes per pixel in LDS (17*16)

typedef int v4i __attribute__((ext_vector_type(4)));

__global__ __launch_bounds__(256)
void pack_x_kernel(const float* __restrict__ x, int8_t* __restrict__ Aq) {
    const int h = blockIdx.x, n = blockIdx.y;
    const int w  = threadIdx.x & 63;   // 0..55 valid
    const int cg = threadIdx.x >> 6;   // 64-channel group
    if (w >= 56) return;
    const float* xp = x + (((size_t)n * C + cg * 64) * H + h) * W + w;
    uint32_t pk[16];
#pragma unroll
    for (int q = 0; q < 16; ++q) {
        uint32_t u = 0;
#pragma unroll
        for (int b = 0; b < 4; ++b) {
            float v = xp[(size_t)(q * 4 + b) * (H * W)];
            uint32_t t = (v < 0.0f) ? 0xFFu : ((v != 0.0f) ? 1u : 0u);
            u |= t << (8 * b);
        }
        pk[q] = u;
    }
    int8_t* dst = Aq + (((size_t)n * HP + h + 1) * HP + w + 1) * C + cg * 64;
#pragma unroll
    for (int q2 = 0; q2 < 4; ++q2) {
        uint4 st; st.x = pk[4*q2]; st.y = pk[4*q2+1]; st.z = pk[4*q2+2]; st.w = pk[4*q2+3];
        *(uint4*)(dst + q2 * 16) = st;
    }
}

__global__ __launch_bounds__(64)
void pack_w_kernel(const float* __restrict__ wa, const float* __restrict__ wb,
                   int8_t* __restrict__ B1, int8_t* __restrict__ B2) {
    const int kstep = blockIdx.x;   // 0..35
    const int nfrag = blockIdx.y;   // 0..15
    const float* wsrc = blockIdx.z ? wb : wa;
    int8_t* dst       = blockIdx.z ? B2 : B1;
    const int lane = threadIdx.x, quad = lane >> 4, l16 = lane & 15;
    const int co = nfrag * 16 + l16;
    uint32_t pk[4];
#pragma unroll
    for (int d = 0; d < 4; ++d) {
        uint32_t u = 0;
#pragma unroll
        for (int bb = 0; bb < 4; ++bb) {
            int k = kstep * 64 + quad * 16 + d * 4 + bb;
            int tap = k >> 8, ci = k & 255;
            float v = wsrc[((size_t)co * C + ci) * 9 + tap];
            uint32_t t = (v < 0.0f) ? 0xFFu : ((v != 0.0f) ? 1u : 0u);
            u |= t << (8 * bb);
        }
        pk[d] = u;
    }
    uint4 st; st.x = pk[0]; st.y = pk[1]; st.z = pk[2]; st.w = pk[3];
    *(uint4*)(dst + ((size_t)(nfrag * 36 + kstep) * 64 + lane) * 16) = st;
}

// STAGE 1: GEMM -> BN -> ternarize -> NHWC i8 out (for conv2).
// STAGE 2: GEMM -> BN -> +residual -> clip -> fp32 NCHW out.
template <int STAGE>
__global__ __launch_bounds__(256, 2)
void mconv_kernel(const int8_t* __restrict__ Aq, const int8_t* __restrict__ Bpk,
                  const float* __restrict__ gamma, const float* __restrict__ beta,
                  const float* __restrict__ mean,  const float* __restrict__ var,
                  const float* __restrict__ resid,
                  int8_t* __restrict__ Bout, float* __restrict__ out) {
    const int h2 = blockIdx.x;   // output row pair: rows h2*2, h2*2+1
    const int n  = blockIdx.y;
    const int tid = threadIdx.x;
    const int wv = tid >> 6, lane = tid & 63, quad = lane >> 4, l16 = lane & 15;

    __shared__ int8_t lds[4 * HP * PPIX];   // 63104 B

    // ---- stage padded-buffer rows h2*2 .. h2*2+3 into LDS ----
    const int8_t* gA = Aq + ((size_t)n * HP + h2 * 2) * HP * C;
    for (int idx = tid; idx < 4 * HP * 16; idx += 256) {   // 3712 16B chunks
        int pix = idx >> 4, c16 = idx & 15;
        v4i val = *(const v4i*)(gA + (size_t)pix * C + c16 * 16);
        *(v4i*)(&lds[pix * PPIX + c16 * 16]) = val;
    }
    __syncthreads();

    // per-lane A-row bases (m = f*16 + l16 -> pixel (hl, w))
    int pixbase[7];
#pragma unroll
    for (int f = 0; f < 7; ++f) {
        int mm = f * 16 + l16;
        int hl = (mm >= 56) ? 1 : 0;
        int w  = mm - 56 * hl;
        pixbase[f] = (hl * HP + w) * PPIX + quad * 16;
    }

    // per-nf B fragment pointers (each wave owns co block wv*64 .. wv*64+63)
    const v4i* bpn[4];
#pragma unroll
    for (int nf = 0; nf < 4; ++nf)
        bpn[nf] = (const v4i*)Bpk + ((size_t)((wv * 4 + nf) * 36) * 64 + lane);

    v4i acc[7][4];
#pragma unroll
    for (int f = 0; f < 7; ++f)
#pragma unroll
        for (int nf = 0; nf < 4; ++nf)
            acc[f][nf] = (v4i){0, 0, 0, 0};

#pragma unroll 1
    for (int tap = 0; tap < 9; ++tap) {
        const int r = tap / 3, c = tap % 3;
        const int Sbase = (r * HP + c) * PPIX;
        int abase[7];
#pragma unroll
        for (int f = 0; f < 7; ++f) abase[f] = pixbase[f] + Sbase;

#pragma unroll
        for (int cich = 0; cich < 4; ++cich) {
            v4i bfr[4];
#pragma unroll
            for (int nf = 0; nf < 4; ++nf)
                bfr[nf] = bpn[nf][(size_t)tap * 256 + cich * 64];
            v4i afr[7];
#pragma unroll
            for (int f = 0; f < 7; ++f)
                afr[f] = *(const v4i*)(&lds[abase[f] + cich * 64]);
#pragma unroll
            for (int f = 0; f < 7; ++f)
#pragma unroll
                for (int nf = 0; nf < 4; ++nf)
                    acc[f][nf] = __builtin_amdgcn_mfma_i32_16x16x64_i8(
                        afr[f], bfr[nf], acc[f][nf], 0, 0, 0);
        }
    }

    // ---- epilogue ----
#pragma unroll
    for (int nf = 0; nf < 4; ++nf) {
        const int co = (wv * 4 + nf) * 16 + l16;
        double sc_d = (double)gamma[co] / sqrt((double)var[co] + 1e-5);
        float scale = (float)sc_d;
        float shift = (float)((double)beta[co] - (double)mean[co] * sc_d);
#pragma unroll
        for (int f = 0; f < 7; ++f) {
#pragma unroll
            for (int reg = 0; reg < 4; ++reg) {
                int mm = f * 16 + quad * 4 + reg;
                int hl = (mm >= 56) ? 1 : 0;
                int w  = mm - 56 * hl;
                int oh = h2 * 2 + hl;
                float v = __fadd_rn(__fmul_rn((float)acc[f][nf][reg], scale), shift);
                if (STAGE == 1) {
                    int8_t t = (v < 0.0f) ? (int8_t)-1 : ((v != 0.0f) ? (int8_t)1 : (int8_t)0);
                    Bout[(((size_t)n * HP + oh + 1) * HP + (w + 1)) * C + co] = t;
                } else {
                    size_t oidx = (((size_t)n * C + co) * H + oh) * W + w;
                    float o = v + resid[oidx];
                    o = fminf(1.0f, fmaxf(-1.0f, o));
                    out[oidx] = o;
                }
            }
        }
    }
}

extern "C" void kernel_launch(void* const* d_in, const int* in_sizes, int n_in,
                              void* d_out, int out_size, void* d_ws, size_t ws_size,
                              hipStream_t stream) {
    const float* x  = (const float*)d_in[0];
    const float* w1 = (const float*)d_in[1];
    const float* g1 = (const float*)d_in[2];
    const float* b1 = (const float*)d_in[3];
    const float* m1 = (const float*)d_in[4];
    const float* v1 = (const float*)d_in[5];
    const float* w2 = (const float*)d_in[6];
    const float* g2 = (const float*)d_in[7];
    const float* b2 = (const float*)d_in[8];
    const float* m2 = (const float*)d_in[9];
    const float* v2 = (const float*)d_in[10];
    float* out = (float*)d_out;

    uint8_t* ws = (uint8_t*)d_ws;
    const size_t ASZ = (size_t)NB * HP * HP * C;       // 55,083,008 B per act buffer
    const size_t WPK = (size_t)16 * 36 * 64 * 16;      // 589,824 B per packed weight
    int8_t* Aq   = (int8_t*)(ws);
    int8_t* Bq   = (int8_t*)(ws + ASZ);
    int8_t* Bpk1 = (int8_t*)(ws + 2 * ASZ);
    int8_t* Bpk2 = (int8_t*)(ws + 2 * ASZ + WPK);

    // zero both activation buffers (provides the zero halos)
    hipMemsetAsync(ws, 0, 2 * ASZ, stream);

    pack_w_kernel<<<dim3(36, 16, 2), 64, 0, stream>>>(w1, w2, Bpk1, Bpk2);
    pack_x_kernel<<<dim3(H, NB), 256, 0, stream>>>(x, Aq);
    mconv_kernel<1><<<dim3(28, NB), 256, 0, stream>>>(Aq, Bpk1, g1, b1, m1, v1,
                                                      nullptr, Bq, nullptr);
    mconv_kernel<2><<<dim3(28, NB), 256, 0, stream>>>(Bq, Bpk2, g2, b2, m2, v2,
                                                      x, nullptr, out);
}